// Round 5
// baseline (396.168 us; speedup 1.0000x reference)
//
#include <hip/hip_runtime.h>
#include <hip/hip_cooperative_groups.h>

namespace cg = cooperative_groups;

#define B_ 128
#define N_ 256
#define M_ 1024
#define EPS_ 1e-16f
#define NORM_EPS_ 1e-8f

#define GRID_ 1024
#define SPLIT_ 8                 // phase-C blocks per batch
#define NSUB_ (N_ / SPLIT_)      // 32 rows per block

typedef float f32x4 __attribute__((ext_vector_type(4)));

__device__ __forceinline__ float wave_reduce_sum(float v) {
#pragma unroll
    for (int off = 32; off; off >>= 1) v += __shfl_xor(v, off, 64);
    return v;
}

__device__ __forceinline__ float wave_reduce_max(float v) {
#pragma unroll
    for (int off = 32; off; off >>= 1) v = fmaxf(v, __shfl_xor(v, off, 64));
    return v;
}

// Single cooperative kernel, 1024 blocks x 256 threads (4 blocks/CU, proven
// co-resident in round 3 at 32 VGPR).
// Phase A: per-row dot(mem,k), ||mem||^2 for this block's 32 rows (8/wave).
// grid.sync()
// Phase BC: per-block weight-pipeline recompute (cheap, x8 redundant per
// batch), then erase/add write + fused read partials on the same 32 rows
// (re-read is L3-hot; plain stores — NO nontemporal hints, round-3 lesson).
__global__ void __launch_bounds__(256, 4)
ntm_kernel(const float* __restrict__ memory,
           const float* __restrict__ k,
           const float* __restrict__ beta,
           const float* __restrict__ g,
           const float* __restrict__ s,
           const float* __restrict__ gamma,
           const float* __restrict__ w_prev,
           const float* __restrict__ e,
           const float* __restrict__ a,
           float* __restrict__ read_out,
           float* __restrict__ newmem_out,
           float* __restrict__ w_out,
           float* __restrict__ dot_ws,
           float* __restrict__ mnorm2_ws) {
    cg::grid_group grid = cg::this_grid();

    const int tid  = threadIdx.x;           // 0..255
    const int lane = tid & 63;
    const int wave = tid >> 6;
    const int blk  = blockIdx.x;

    __shared__ float red[4];
    __shared__ float s_wg[N_];

    // zero-init read_out (d_out poisoned 0xAA): 1024 blocks * 128 = B_*M_
    if (tid < 128) read_out[blk * 128 + tid] = 0.f;

    // ---------------- Phase A ----------------
    {
        const int b = blk >> 3;             // 8 blocks per batch
        const f32x4* __restrict__ krow = (const f32x4*)(k + (size_t)b * M_);
        // hoist k fragments into registers, reused across this wave's 8 rows
        const f32x4 kv0 = krow[0 * 64 + lane];
        const f32x4 kv1 = krow[1 * 64 + lane];
        const f32x4 kv2 = krow[2 * 64 + lane];
        const f32x4 kv3 = krow[3 * 64 + lane];

        for (int j = 0; j < 8; ++j) {       // 8 rows per wave
            const int row = blk * (NSUB_) + wave * 8 + j;   // 32 rows/block
            const f32x4* __restrict__ mrow = (const f32x4*)(memory + (size_t)row * M_);
            const f32x4 m0 = mrow[0 * 64 + lane];
            const f32x4 m1 = mrow[1 * 64 + lane];
            const f32x4 m2 = mrow[2 * 64 + lane];
            const f32x4 m3 = mrow[3 * 64 + lane];
            // EPS (1e-16) dropped: contributes ~1e-14 absolute, threshold 0.108
            float dacc = m0.x * kv0.x + m0.y * kv0.y + m0.z * kv0.z + m0.w * kv0.w
                       + m1.x * kv1.x + m1.y * kv1.y + m1.z * kv1.z + m1.w * kv1.w
                       + m2.x * kv2.x + m2.y * kv2.y + m2.z * kv2.z + m2.w * kv2.w
                       + m3.x * kv3.x + m3.y * kv3.y + m3.z * kv3.z + m3.w * kv3.w;
            float nacc = m0.x * m0.x + m0.y * m0.y + m0.z * m0.z + m0.w * m0.w
                       + m1.x * m1.x + m1.y * m1.y + m1.z * m1.z + m1.w * m1.w
                       + m2.x * m2.x + m2.y * m2.y + m2.z * m2.z + m2.w * m2.w
                       + m3.x * m3.x + m3.y * m3.y + m3.z * m3.z + m3.w * m3.w;
            dacc = wave_reduce_sum(dacc);
            nacc = wave_reduce_sum(nacc);
            if (lane == 0) {
                dot_ws[row]    = dacc;
                mnorm2_ws[row] = nacc;
            }
        }
    }

    grid.sync();

    // ---------------- Phase B (recomputed per block) ----------------
    const int b    = blk >> 3;
    const int part = blk & (SPLIT_ - 1);
    const int n    = tid;

    {
        // knorm (identical to validated round-4 code)
        f32x4 kv = ((const f32x4*)(k + (size_t)b * M_))[tid];
        float k0 = kv.x + EPS_, k1 = kv.y + EPS_, k2 = kv.z + EPS_, k3 = kv.w + EPS_;
        float kk = k0 * k0 + k1 * k1 + k2 * k2 + k3 * k3;
        kk = wave_reduce_sum(kk);
        if (lane == 0) red[wave] = kk;
        __syncthreads();
        const float knorm = fmaxf(sqrtf(red[0] + red[1] + red[2] + red[3]), NORM_EPS_);
        __syncthreads();

        // cosine + beta
        const float mnorm = fmaxf(sqrtf(mnorm2_ws[(size_t)b * N_ + n]), NORM_EPS_);
        const float cosv  = dot_ws[(size_t)b * N_ + n] / (mnorm * knorm);
        const float x     = beta[b] * cosv;

        // softmax over n
        float mx = wave_reduce_max(x);
        if (lane == 0) red[wave] = mx;
        __syncthreads();
        mx = fmaxf(fmaxf(red[0], red[1]), fmaxf(red[2], red[3]));
        __syncthreads();
        const float ex = __expf(x - mx);
        float es = wave_reduce_sum(ex);
        if (lane == 0) red[wave] = es;
        __syncthreads();
        es = red[0] + red[1] + red[2] + red[3];
        __syncthreads();
        const float w_c = ex / es;

        // interpolate
        const float gb  = g[b];
        const float w_g = gb * w_c + (1.f - gb) * w_prev[(size_t)b * N_ + n];
        s_wg[n] = w_g;
        __syncthreads();

        // circular 3-tap shift
        const float s0 = s[b * 3 + 0], s1 = s[b * 3 + 1], s2 = s[b * 3 + 2];
        const float w_t = s0 * s_wg[(n + N_ - 1) & (N_ - 1)]
                        + s1 * s_wg[n]
                        + s2 * s_wg[(n + 1) & (N_ - 1)];
        __syncthreads();   // all shift reads done before s_wg is overwritten

        // sharpen
        const float w_pow = powf(w_t, gamma[b]);
        float ps = wave_reduce_sum(w_pow);
        if (lane == 0) red[wave] = ps;
        __syncthreads();
        ps = red[0] + red[1] + red[2] + red[3];
        const float w_final = w_pow / (ps + EPS_);

        s_wg[n] = w_final;                  // reuse s_wg for final w
        if (part == 0) w_out[(size_t)b * N_ + n] = w_final;
        __syncthreads();
    }

    // ---------------- Phase C ----------------
    {
        const f32x4 ev = ((const f32x4*)(e + (size_t)b * M_))[tid];
        const f32x4 av = ((const f32x4*)(a + (size_t)b * M_))[tid];

        const size_t base = (size_t)b * N_ * M_;
        f32x4 racc = {0.f, 0.f, 0.f, 0.f};

#pragma unroll 4
        for (int j = 0; j < NSUB_; ++j) {
            const int nn = part * NSUB_ + j;
            const f32x4 mv = ((const f32x4*)(memory + base + (size_t)nn * M_))[tid];
            const float wn = s_wg[nn];
            f32x4 nv;
            nv.x = mv.x * (1.f - wn * ev.x) + wn * av.x;
            nv.y = mv.y * (1.f - wn * ev.y) + wn * av.y;
            nv.z = mv.z * (1.f - wn * ev.z) + wn * av.z;
            nv.w = mv.w * (1.f - wn * ev.w) + wn * av.w;
            ((f32x4*)(newmem_out + base + (size_t)nn * M_))[tid] = nv;
            racc.x += wn * nv.x;
            racc.y += wn * nv.y;
            racc.z += wn * nv.z;
            racc.w += wn * nv.w;
        }

        float* rrow = read_out + (size_t)b * M_ + tid * 4;
        atomicAdd(rrow + 0, racc.x);
        atomicAdd(rrow + 1, racc.y);
        atomicAdd(rrow + 2, racc.z);
        atomicAdd(rrow + 3, racc.w);
    }
}

extern "C" void kernel_launch(void* const* d_in, const int* in_sizes, int n_in,
                              void* d_out, int out_size, void* d_ws, size_t ws_size,
                              hipStream_t stream) {
    (void)in_sizes; (void)n_in; (void)out_size; (void)ws_size;

    const float* memory = (const float*)d_in[0];
    const float* k      = (const float*)d_in[1];
    const float* beta   = (const float*)d_in[2];
    const float* g      = (const float*)d_in[3];
    const float* s      = (const float*)d_in[4];
    const float* gamma  = (const float*)d_in[5];
    const float* w_prev = (const float*)d_in[6];
    const float* e      = (const float*)d_in[7];
    const float* a      = (const float*)d_in[8];

    float* out        = (float*)d_out;
    float* read_out   = out;                                 // B*M
    float* newmem_out = out + (size_t)B_ * M_;               // B*N*M
    float* w_out      = newmem_out + (size_t)B_ * N_ * M_;   // B*N

    float* ws        = (float*)d_ws;
    float* dot_ws    = ws;                                   // B*N
    float* mnorm2_ws = ws + (size_t)B_ * N_;                 // B*N

    void* args[] = {
        (void*)&memory, (void*)&k, (void*)&beta, (void*)&g, (void*)&s,
        (void*)&gamma, (void*)&w_prev, (void*)&e, (void*)&a,
        (void*)&read_out, (void*)&newmem_out, (void*)&w_out,
        (void*)&dot_ws, (void*)&mnorm2_ws
    };
    hipLaunchCooperativeKernel((const void*)ntm_kernel,
                               dim3(GRID_), dim3(256), args, 0, stream);
}

// Round 6
// 277.423 us; speedup vs baseline: 1.4280x; 1.4280x over previous
//
#include <hip/hip_runtime.h>

#define B_ 128
#define N_ 256
#define M_ 1024
#define EPS_ 1e-16f
#define NORM_EPS_ 1e-8f

#define SPLIT_ 16                // write/read blocks per batch
#define NSUB_ (N_ / SPLIT_)      // 16 rows per fused block
#define SIMROWS_ 16              // rows per sim block (4 per wave)

typedef float f32x4 __attribute__((ext_vector_type(4)));

__device__ __forceinline__ float wave_reduce_sum(float v) {
#pragma unroll
    for (int off = 32; off; off >>= 1) v += __shfl_xor(v, off, 64);
    return v;
}

__device__ __forceinline__ float wave_reduce_max(float v) {
#pragma unroll
    for (int off = 32; off; off >>= 1) v = fmaxf(v, __shfl_xor(v, off, 64));
    return v;
}

// ---------------- Pass 1: per-row dot(mem,k) and ||mem||^2 ----------------
// grid: (B*N)/SIMROWS_ = 2048 blocks, 256 threads. Each wave: 4 rows, k
// hoisted into registers. Also zero-inits read_out (blocks 0..511).
// EPS (1e-16) dropped from dot/norm: contributes ~1e-14 abs, threshold 0.108.
__global__ void sim_kernel(const float* __restrict__ memory,
                           const float* __restrict__ k,
                           float* __restrict__ dot_out,
                           float* __restrict__ mnorm2_out,
                           float* __restrict__ read_out) {
    const int wave = threadIdx.x >> 6;
    const int lane = threadIdx.x & 63;
    const int blk  = blockIdx.x;
    const int b    = blk >> 4;                     // 16 blocks per batch

    // zero-init read output (d_out is poisoned 0xAA before every launch)
    if (blk < (B_ * M_) / 256) {
        read_out[blk * 256 + threadIdx.x] = 0.f;
    }

    const f32x4* __restrict__ krow = (const f32x4*)(k + (size_t)b * M_);
    const f32x4 kv0 = krow[0 * 64 + lane];
    const f32x4 kv1 = krow[1 * 64 + lane];
    const f32x4 kv2 = krow[2 * 64 + lane];
    const f32x4 kv3 = krow[3 * 64 + lane];

#pragma unroll
    for (int j = 0; j < 4; ++j) {                  // 4 rows per wave
        const int row = blk * SIMROWS_ + wave * 4 + j;
        const f32x4* __restrict__ mrow = (const f32x4*)(memory + (size_t)row * M_);
        const f32x4 m0 = mrow[0 * 64 + lane];
        const f32x4 m1 = mrow[1 * 64 + lane];
        const f32x4 m2 = mrow[2 * 64 + lane];
        const f32x4 m3 = mrow[3 * 64 + lane];
        float dacc = m0.x * kv0.x + m0.y * kv0.y + m0.z * kv0.z + m0.w * kv0.w
                   + m1.x * kv1.x + m1.y * kv1.y + m1.z * kv1.z + m1.w * kv1.w
                   + m2.x * kv2.x + m2.y * kv2.y + m2.z * kv2.z + m2.w * kv2.w
                   + m3.x * kv3.x + m3.y * kv3.y + m3.z * kv3.z + m3.w * kv3.w;
        float nacc = m0.x * m0.x + m0.y * m0.y + m0.z * m0.z + m0.w * m0.w
                   + m1.x * m1.x + m1.y * m1.y + m1.z * m1.z + m1.w * m1.w
                   + m2.x * m2.x + m2.y * m2.y + m2.z * m2.z + m2.w * m2.w
                   + m3.x * m3.x + m3.y * m3.y + m3.z * m3.z + m3.w * m3.w;
        dacc = wave_reduce_sum(dacc);
        nacc = wave_reduce_sum(nacc);
        if (lane == 0) {
            dot_out[row]    = dacc;
            mnorm2_out[row] = nacc;
        }
    }
}

// ---------------- Pass 2: weight pipeline (recomputed per block) + write + read ----------------
// grid: B*SPLIT_ = 2048 blocks, 256 threads. Each block: per-b weight
// pipeline (cheap, redundant x16), then erase/add + read partials on 16 rows.
__global__ void fused_weight_write_kernel(const float* __restrict__ memory,
                                          const float* __restrict__ k,
                                          const float* __restrict__ beta,
                                          const float* __restrict__ g,
                                          const float* __restrict__ s,
                                          const float* __restrict__ gamma,
                                          const float* __restrict__ w_prev,
                                          const float* __restrict__ e,
                                          const float* __restrict__ a,
                                          const float* __restrict__ dot_in,
                                          const float* __restrict__ mnorm2_in,
                                          float* __restrict__ w_out,
                                          float* __restrict__ newmem_out,
                                          float* __restrict__ read_out) {
    const int b    = blockIdx.x >> 4;              // / SPLIT_
    const int part = blockIdx.x & (SPLIT_ - 1);
    const int tid  = threadIdx.x;                  // 0..255
    const int lane = tid & 63;
    const int wave = tid >> 6;
    const int n    = tid;

    __shared__ float red[4];
    __shared__ float s_wg[N_];

    // hoist e/a row loads: latency hides under the weight pipeline
    const f32x4 ev = ((const f32x4*)(e + (size_t)b * M_))[tid];
    const f32x4 av = ((const f32x4*)(a + (size_t)b * M_))[tid];

    // ---- knorm = max(||k+eps||, 1e-8) ----
    f32x4 kv = ((const f32x4*)(k + (size_t)b * M_))[tid];
    float k0 = kv.x + EPS_, k1 = kv.y + EPS_, k2 = kv.z + EPS_, k3 = kv.w + EPS_;
    float kk = k0 * k0 + k1 * k1 + k2 * k2 + k3 * k3;
    kk = wave_reduce_sum(kk);
    if (lane == 0) red[wave] = kk;
    __syncthreads();
    const float knorm = fmaxf(sqrtf(red[0] + red[1] + red[2] + red[3]), NORM_EPS_);
    __syncthreads();

    // ---- cosine + beta ----
    const float mnorm = fmaxf(sqrtf(mnorm2_in[(size_t)b * N_ + n]), NORM_EPS_);
    const float cosv  = dot_in[(size_t)b * N_ + n] / (mnorm * knorm);
    const float x     = beta[b] * cosv;

    // ---- softmax over n ----
    float mx = wave_reduce_max(x);
    if (lane == 0) red[wave] = mx;
    __syncthreads();
    mx = fmaxf(fmaxf(red[0], red[1]), fmaxf(red[2], red[3]));
    __syncthreads();
    const float ex = __expf(x - mx);
    float es = wave_reduce_sum(ex);
    if (lane == 0) red[wave] = es;
    __syncthreads();
    es = red[0] + red[1] + red[2] + red[3];
    __syncthreads();
    const float w_c = ex / es;

    // ---- interpolate ----
    const float gb  = g[b];
    const float w_g = gb * w_c + (1.f - gb) * w_prev[(size_t)b * N_ + n];
    s_wg[n] = w_g;
    __syncthreads();

    // ---- circular 3-tap shift ----
    const float s0 = s[b * 3 + 0], s1 = s[b * 3 + 1], s2 = s[b * 3 + 2];
    const float w_t = s0 * s_wg[(n + N_ - 1) & (N_ - 1)]
                    + s1 * s_wg[n]
                    + s2 * s_wg[(n + 1) & (N_ - 1)];
    __syncthreads();   // all shift reads done before s_wg is overwritten

    // ---- sharpen ----
    const float w_pow = powf(w_t, gamma[b]);
    float ps = wave_reduce_sum(w_pow);
    if (lane == 0) red[wave] = ps;
    __syncthreads();
    ps = red[0] + red[1] + red[2] + red[3];
    const float w_final = w_pow / (ps + EPS_);

    s_wg[n] = w_final;                  // reuse s_wg to hold final w
    if (part == 0) w_out[(size_t)b * N_ + n] = w_final;
    __syncthreads();

    // ---- write (erase/add) + fused read partials over this block's 16 rows ----
    const size_t base = (size_t)b * N_ * M_;
    f32x4 racc = {0.f, 0.f, 0.f, 0.f};

#pragma unroll 4
    for (int j = 0; j < NSUB_; ++j) {
        const int nn = part * NSUB_ + j;
        const f32x4 mv = ((const f32x4*)(memory + base + (size_t)nn * M_))[tid];
        const float wn = s_wg[nn];
        f32x4 nv;
        nv.x = mv.x * (1.f - wn * ev.x) + wn * av.x;
        nv.y = mv.y * (1.f - wn * ev.y) + wn * av.y;
        nv.z = mv.z * (1.f - wn * ev.z) + wn * av.z;
        nv.w = mv.w * (1.f - wn * ev.w) + wn * av.w;
        ((f32x4*)(newmem_out + base + (size_t)nn * M_))[tid] = nv;
        racc.x += wn * nv.x;
        racc.y += wn * nv.y;
        racc.z += wn * nv.z;
        racc.w += wn * nv.w;
    }

    float* rrow = read_out + (size_t)b * M_ + tid * 4;
    atomicAdd(rrow + 0, racc.x);
    atomicAdd(rrow + 1, racc.y);
    atomicAdd(rrow + 2, racc.z);
    atomicAdd(rrow + 3, racc.w);
}

extern "C" void kernel_launch(void* const* d_in, const int* in_sizes, int n_in,
                              void* d_out, int out_size, void* d_ws, size_t ws_size,
                              hipStream_t stream) {
    (void)in_sizes; (void)n_in; (void)out_size; (void)ws_size;

    const float* memory = (const float*)d_in[0];
    const float* k      = (const float*)d_in[1];
    const float* beta   = (const float*)d_in[2];
    const float* g      = (const float*)d_in[3];
    const float* s      = (const float*)d_in[4];
    const float* gamma  = (const float*)d_in[5];
    const float* w_prev = (const float*)d_in[6];
    const float* e      = (const float*)d_in[7];
    const float* a      = (const float*)d_in[8];

    float* out        = (float*)d_out;
    float* read_out   = out;                                 // B*M
    float* newmem_out = out + (size_t)B_ * M_;               // B*N*M
    float* w_out      = newmem_out + (size_t)B_ * N_ * M_;   // B*N

    float* ws        = (float*)d_ws;
    float* dot_ws    = ws;                                   // B*N
    float* mnorm2_ws = ws + (size_t)B_ * N_;                 // B*N

    sim_kernel<<<(B_ * N_) / SIMROWS_, 256, 0, stream>>>(memory, k, dot_ws,
                                                         mnorm2_ws, read_out);
    fused_weight_write_kernel<<<B_ * SPLIT_, 256, 0, stream>>>(
        memory, k, beta, g, s, gamma, w_prev, e, a,
        dot_ws, mnorm2_ws, w_out, newmem_out, read_out);
}